// Round 10
// baseline (84.655 us; speedup 1.0000x reference)
//
#include <hip/hip_runtime.h>
#include <cstdint>
#include <cstddef>

#define E_DIM 1024
#define PD 64            // proj dim
#define NP 128           // 2*proj dim
#define B_DIM 8
#define S_DIM 2048
#define M_TOT (B_DIM * S_DIM)   // 16384

#define BMR 32           // rows per block
#define BK 32
#define NCH (E_DIM / BK) // 32 chunks

typedef __attribute__((ext_vector_type(8))) short short8v;  // 8 bf16 (4 VGPR)
typedef __attribute__((ext_vector_type(4))) float f32x4;    // MFMA acc / vec IO

__device__ __forceinline__ void gload16(const void* g, void* l) {
    __builtin_amdgcn_global_load_lds(
        (const __attribute__((address_space(1))) unsigned int*)g,
        (__attribute__((address_space(3))) unsigned int*)(uintptr_t)l,
        16, 0, 0);
}

// two-fold truncation split: a = hi + lo at the fp32->bf16 boundary
__device__ __forceinline__ void cvt_hilo(const f32x4 v0, const f32x4 v1,
                                         short8v& h, short8v& l) {
    const unsigned MSK = 0xFFFF0000u;
    unsigned a0 = __float_as_uint(v0.x), a1 = __float_as_uint(v0.y);
    unsigned a2 = __float_as_uint(v0.z), a3 = __float_as_uint(v0.w);
    unsigned a4 = __float_as_uint(v1.x), a5 = __float_as_uint(v1.y);
    unsigned a6 = __float_as_uint(v1.z), a7 = __float_as_uint(v1.w);
    float l0 = v0.x - __uint_as_float(a0 & MSK);
    float l1 = v0.y - __uint_as_float(a1 & MSK);
    float l2 = v0.z - __uint_as_float(a2 & MSK);
    float l3 = v0.w - __uint_as_float(a3 & MSK);
    float l4 = v1.x - __uint_as_float(a4 & MSK);
    float l5 = v1.y - __uint_as_float(a5 & MSK);
    float l6 = v1.z - __uint_as_float(a6 & MSK);
    float l7 = v1.w - __uint_as_float(a7 & MSK);
    union { unsigned u[4]; short8v s; } H, L;
    H.u[0] = (a1 & MSK) | (a0 >> 16);
    H.u[1] = (a3 & MSK) | (a2 >> 16);
    H.u[2] = (a5 & MSK) | (a4 >> 16);
    H.u[3] = (a7 & MSK) | (a6 >> 16);
    L.u[0] = (__float_as_uint(l1) & MSK) | (__float_as_uint(l0) >> 16);
    L.u[1] = (__float_as_uint(l3) & MSK) | (__float_as_uint(l2) >> 16);
    L.u[2] = (__float_as_uint(l5) & MSK) | (__float_as_uint(l4) >> 16);
    L.u[3] = (__float_as_uint(l7) & MSK) | (__float_as_uint(l6) >> 16);
    h = H.s; l = L.s;
}

// ---------------- K0: pre-convert W -> bf16 hi/lo images in staged layout ----------------
// img[ch][kq][col][8] bf16: exactly the per-chunk LDS byte order gemm stages.
__global__ __launch_bounds__(256) void conv_w(const float* __restrict__ W,
                                              ushort* __restrict__ hiImg,
                                              ushort* __restrict__ loImg) {
    const int t = blockIdx.x * 256 + threadIdx.x;  // 16384 threads
    const int c  = t & 127;
    const int q  = (t >> 7) & 3;
    const int ch = t >> 9;
    const float* src = W + (size_t)c * E_DIM + ch * 32 + q * 8;
    const f32x4 v0 = *(const f32x4*)src;
    const f32x4 v1 = *(const f32x4*)(src + 4);
    short8v h, l;
    cvt_hilo(v0, v1, h, l);
    const size_t off = ((size_t)(ch * 4 + q) * NP + c) * 8;
    *(short8v*)&hiImg[off] = h;
    *(short8v*)&loImg[off] = l;
}

// ---------------- K1: single-pass bf16-MFMA GEMM, bias fused ----------------
// qk[m][p] = sum_k A[m][k]*W[p][k] + bias[p];  A = context as (S*B,E), m = s*B+b.
// 256 thr = 4 waves; wave w -> cols w*32..+31, all 32 rows. 16x16x32 bf16 MFMA,
// hi/lo split on A (in-kernel cvt) and W (pre-converted images, direct b128 frags).
// A staged via global_load_lds into linear [row][32] f32 with source-granule XOR
// (key=row&7); W staged via fully-linear 1KB gload16 from the images.
__global__ __launch_bounds__(256, 2) void gemm_qk(const float* __restrict__ A,
                                                  const ushort* __restrict__ hiImg,
                                                  const ushort* __restrict__ loImg,
                                                  const float* __restrict__ bias,
                                                  float* __restrict__ qk) {
    __shared__ __align__(16) float  As[2][BMR][BK];   // 8 KB
    __shared__ __align__(16) ushort Whi[2][4][NP][8]; // 16 KB
    __shared__ __align__(16) ushort Wlo[2][4][NP][8]; // 16 KB  (40 KB total)
    const int tid = threadIdx.x;
    const int m0  = blockIdx.x * BMR;
    const int w   = __builtin_amdgcn_readfirstlane(tid >> 6);  // wave id (uniform)
    const int ln  = tid & 63;
    const int lr  = ln >> 3;        // staging row in 8-row group
    const int g8  = ln & 7;         // staging slot granule
    const int row16 = ln & 15;      // frag row/col
    const int kq    = ln >> 4;      // k-quadrant
    const int r7    = row16 & 7;
    const int sg0 = ((((kq << 1) | 0) ^ r7) & 7) << 2;  // A slot offsets (floats)
    const int sg1 = ((((kq << 1) | 1) ^ r7) & 7) << 2;

    // A staging source: wave w covers rows w*8..+7; slot s holds global granule s^(row&7)
    const float*  aS = A + (size_t)(m0 + w * 8 + lr) * E_DIM + ((g8 ^ lr) << 2);
    // W staging source: linear; per-lane = base + ln*16B
    const ushort* hS = hiImg + (size_t)(w * 2) * 512 + ln * 8;
    const ushort* lS = loImg + (size_t)(w * 2) * 512 + ln * 8;

    float bias2[2];
    bias2[0] = bias[w * 32 + row16];
    bias2[1] = bias[w * 32 + 16 + row16];

    f32x4 acc[2][2];
#pragma unroll
    for (int i = 0; i < 2; ++i)
#pragma unroll
        for (int j = 0; j < 2; ++j) acc[i][j] = (f32x4){0.f, 0.f, 0.f, 0.f};

#define STAGE(BUF, CH)                                                          \
    {                                                                           \
        gload16(aS + (size_t)(CH) * BK, &As[BUF][w * 8][0]);                    \
        gload16(hS + (size_t)(CH) * 4096,       (ushort*)Whi[BUF] + (w * 2) * 512);       \
        gload16(hS + (size_t)(CH) * 4096 + 512, (ushort*)Whi[BUF] + (w * 2 + 1) * 512);   \
        gload16(lS + (size_t)(CH) * 4096,       (ushort*)Wlo[BUF] + (w * 2) * 512);       \
        gload16(lS + (size_t)(CH) * 4096 + 512, (ushort*)Wlo[BUF] + (w * 2 + 1) * 512);   \
    }

    STAGE(0, 0)

    for (int ch = 0; ch < NCH; ++ch) {
        const int buf = ch & 1;
        __syncthreads();   // drains vmcnt -> staged chunk valid
        if (ch + 1 < NCH) {
            STAGE(buf ^ 1, ch + 1)
        }
        short8v ah[2], al[2];
#pragma unroll
        for (int fi = 0; fi < 2; ++fi) {
            const float* base = &As[buf][fi * 16 + row16][0];
            const f32x4 v0 = *(const f32x4*)(base + sg0);
            const f32x4 v1 = *(const f32x4*)(base + sg1);
            cvt_hilo(v0, v1, ah[fi], al[fi]);
        }
        short8v wh[2], wl[2];
#pragma unroll
        for (int fj = 0; fj < 2; ++fj) {
            wh[fj] = *(const short8v*)&Whi[buf][kq][w * 32 + fj * 16 + row16][0];
            wl[fj] = *(const short8v*)&Wlo[buf][kq][w * 32 + fj * 16 + row16][0];
        }
#pragma unroll
        for (int fi = 0; fi < 2; ++fi)
#pragma unroll
            for (int fj = 0; fj < 2; ++fj) {
                acc[fi][fj] = __builtin_amdgcn_mfma_f32_16x16x32_bf16(
                    ah[fi], wh[fj], acc[fi][fj], 0, 0, 0);
                acc[fi][fj] = __builtin_amdgcn_mfma_f32_16x16x32_bf16(
                    ah[fi], wl[fj], acc[fi][fj], 0, 0, 0);
                acc[fi][fj] = __builtin_amdgcn_mfma_f32_16x16x32_bf16(
                    al[fi], wh[fj], acc[fi][fj], 0, 0, 0);
            }
    }
#undef STAGE

    // C/D layout (m89): col = lane&15, row = (lane>>4)*4 + r
#pragma unroll
    for (int fi = 0; fi < 2; ++fi)
#pragma unroll
        for (int fj = 0; fj < 2; ++fj) {
#pragma unroll
            for (int r = 0; r < 4; ++r) {
                const int m = m0 + fi * 16 + kq * 4 + r;
                const int p = w * 32 + fj * 16 + row16;
                qk[(size_t)m * NP + p] = acc[fi][fj][r] + bias2[fj];
            }
        }
}

// ---------------- K2: neighbor scores + 2-way softmax (bias already in qk) ----------------
__global__ __launch_bounds__(256) void neighbor_probs(const float* __restrict__ qk,
                                                      float* __restrict__ p0,
                                                      float* __restrict__ p1) {
    const int m = blockIdx.x * 4 + (threadIdx.x >> 6);  // position index m = s*B+b
    const int lane = threadIdx.x & 63;
    const int s = m >> 3;   // / B_DIM
    const int b = m & 7;    // % B_DIM

    const float q = qk[(size_t)m * NP + lane];
    const float kn = (s < S_DIM - 1) ? qk[(size_t)(m + B_DIM) * NP + PD + lane] : 0.f;
    const float kp = (s > 0) ? qk[(size_t)(m - B_DIM) * NP + PD + lane] : 0.f;
    float f = q * kn;   // fwd partial: query[s] . key[s+1]
    float g = q * kp;   // bwd partial: query[s] . key[s-1]
#pragma unroll
    for (int off = 32; off; off >>= 1) {
        f += __shfl_xor(f, off);
        g += __shfl_xor(g, off);
    }
    if (lane == 0) {
        const float s0 = f * (1.f / (float)E_DIM);
        const float s1 = g * (1.f / (float)E_DIM);
        float P0, P1;
        if (s == S_DIM - 1) { P0 = 0.f; P1 = 1.f; }
        else if (s == 0)    { P0 = 1.f; P1 = 0.f; }
        else {
            const float mx = fmaxf(s0, s1);
            const float e0 = __expf(s0 - mx), e1 = __expf(s1 - mx);
            const float inv = 1.f / (e0 + e1);
            P0 = e0 * inv; P1 = e1 * inv;
        }
        p0[b * S_DIM + s] = P0;
        p1[b * S_DIM + s] = P1;
    }
}

// ---------------- K3: combine (flat roll), neighbor_attn out, log, exclusive scan ----------------
__global__ __launch_bounds__(256) void combine_scan(const float* __restrict__ p0,
                                                    const float* __restrict__ p1,
                                                    const float* __restrict__ prior,
                                                    float* __restrict__ out_na,
                                                    float* __restrict__ cs) {
    const int b = blockIdx.x;
    const int tid = threadIdx.x;
    __shared__ float sh[256];

    const int base = b * S_DIM + tid * 8;
    float incl[8];
    float run = 0.f;
#pragma unroll
    for (int u = 0; u < 8; ++u) {
        const int fidx = base + u;
        int nf = fidx + 1;
        if (nf == B_DIM * S_DIM) nf = 0;   // torch .roll on flattened tensor wraps globally
        const float P0 = p0[fidx];
        const float sp = p1[nf];
        const float pr = prior[fidx];
        const float na = pr + (1.f - pr) * sqrtf(P0 * sp + 1e-6f);
        out_na[fidx] = na;
        run += __logf(na);
        incl[u] = run;
    }
    sh[tid] = run;
    __syncthreads();
    for (int off = 1; off < 256; off <<= 1) {
        float v = sh[tid];
        if (tid >= off) v += sh[tid - off];
        __syncthreads();
        sh[tid] = v;
        __syncthreads();
    }
    const float offset = (tid > 0) ? sh[tid - 1] : 0.f;
#pragma unroll
    for (int u = 0; u < 8; ++u) {
        cs[base + u] = offset + ((u > 0) ? incl[u - 1] : 0.f);  // exclusive prefix
    }
}

// ---------------- K4: big output C[b,i,j] = exp(sign*(cs[j]-cs[i])), 0 on diag ----------------
__global__ __launch_bounds__(256) void big_out(const float* __restrict__ cs,
                                               float* __restrict__ out) {
    const int bi = blockIdx.x;          // b*S + i
    const int b = bi >> 11;             // / S_DIM
    const int i = bi & (S_DIM - 1);
    const float ci = cs[b * S_DIM + i];
    const float* crow = cs + (size_t)b * S_DIM;
    float* orow = out + (size_t)bi * S_DIM;
    const int j0 = threadIdx.x * 8;
#pragma unroll
    for (int h = 0; h < 2; ++h) {
        const int j = j0 + h * 4;
        const f32x4 cj = *(const f32x4*)&crow[j];
        f32x4 o;
        {
            const int jj = j + 0; const float m = (jj > i) ? (cj.x - ci) : (ci - cj.x);
            o.x = (jj == i) ? 0.f : __expf(m);
        }
        {
            const int jj = j + 1; const float m = (jj > i) ? (cj.y - ci) : (ci - cj.y);
            o.y = (jj == i) ? 0.f : __expf(m);
        }
        {
            const int jj = j + 2; const float m = (jj > i) ? (cj.z - ci) : (ci - cj.z);
            o.z = (jj == i) ? 0.f : __expf(m);
        }
        {
            const int jj = j + 3; const float m = (jj > i) ? (cj.w - ci) : (ci - cj.w);
            o.w = (jj == i) ? 0.f : __expf(m);
        }
        __builtin_nontemporal_store(o, (f32x4*)&orow[j]);
    }
}

extern "C" void kernel_launch(void* const* d_in, const int* in_sizes, int n_in,
                              void* d_out, int out_size, void* d_ws, size_t ws_size,
                              hipStream_t stream) {
    const float* context = (const float*)d_in[0];   // (S,B,E) fp32
    const float* prior   = (const float*)d_in[1];   // (B,S) fp32
    const float* W       = (const float*)d_in[2];   // (128,1024) fp32
    const float* bias    = (const float*)d_in[3];   // (128,) fp32
    float* out = (float*)d_out;

    float* qk = (float*)d_ws;                          // 16384*128 floats (8 MB)
    float* p0 = qk + (size_t)M_TOT * NP;               // 16384 floats
    float* p1 = p0 + M_TOT;                            // 16384 floats
    float* cs = p1 + M_TOT;                            // 16384 floats
    // W bf16 hi/lo images (256 KB each) live in d_out's C-region; conv_w writes,
    // gemm reads, big_out overwrites afterwards (stream-ordered, safe)
    ushort* hiImg = (ushort*)out;                      // 128K ushorts
    ushort* loImg = hiImg + (size_t)NP * E_DIM;        // 128K ushorts
    float* na_out = out + (size_t)B_DIM * S_DIM * S_DIM;  // second output

    conv_w<<<64, 256, 0, stream>>>(W, hiImg, loImg);
    gemm_qk<<<M_TOT / BMR, 256, 0, stream>>>(context, hiImg, loImg, bias, qk);
    neighbor_probs<<<M_TOT / 4, 256, 0, stream>>>(qk, p0, p1);
    combine_scan<<<B_DIM, 256, 0, stream>>>(p0, p1, prior, na_out, cs);
    big_out<<<M_TOT, 256, 0, stream>>>(cs, out);
}

// Round 11
// 64.494 us; speedup vs baseline: 1.3126x; 1.3126x over previous
//
#include <hip/hip_runtime.h>
#include <cstdint>
#include <cstddef>

#define E_DIM 1024
#define PD 64            // proj dim
#define NP 128           // 2*proj dim
#define B_DIM 8
#define S_DIM 2048
#define M_TOT (B_DIM * S_DIM)   // 16384

#define BMR 32           // rows per block
#define BK 32
#define NCH (E_DIM / BK) // 32 chunks

typedef __attribute__((ext_vector_type(8))) short short8v;  // 8 bf16 (4 VGPR)
typedef __attribute__((ext_vector_type(4))) float f32x4;    // MFMA acc / vec IO

__device__ __forceinline__ void gload16(const void* g, void* l) {
    __builtin_amdgcn_global_load_lds(
        (const __attribute__((address_space(1))) unsigned int*)g,
        (__attribute__((address_space(3))) unsigned int*)(uintptr_t)l,
        16, 0, 0);
}

// two-fold truncation split: a = hi + lo at the fp32->bf16 boundary
__device__ __forceinline__ void cvt_hilo(const f32x4 v0, const f32x4 v1,
                                         short8v& h, short8v& l) {
    const unsigned MSK = 0xFFFF0000u;
    unsigned a0 = __float_as_uint(v0.x), a1 = __float_as_uint(v0.y);
    unsigned a2 = __float_as_uint(v0.z), a3 = __float_as_uint(v0.w);
    unsigned a4 = __float_as_uint(v1.x), a5 = __float_as_uint(v1.y);
    unsigned a6 = __float_as_uint(v1.z), a7 = __float_as_uint(v1.w);
    float l0 = v0.x - __uint_as_float(a0 & MSK);
    float l1 = v0.y - __uint_as_float(a1 & MSK);
    float l2 = v0.z - __uint_as_float(a2 & MSK);
    float l3 = v0.w - __uint_as_float(a3 & MSK);
    float l4 = v1.x - __uint_as_float(a4 & MSK);
    float l5 = v1.y - __uint_as_float(a5 & MSK);
    float l6 = v1.z - __uint_as_float(a6 & MSK);
    float l7 = v1.w - __uint_as_float(a7 & MSK);
    union { unsigned u[4]; short8v s; } H, L;
    H.u[0] = (a1 & MSK) | (a0 >> 16);
    H.u[1] = (a3 & MSK) | (a2 >> 16);
    H.u[2] = (a5 & MSK) | (a4 >> 16);
    H.u[3] = (a7 & MSK) | (a6 >> 16);
    L.u[0] = (__float_as_uint(l1) & MSK) | (__float_as_uint(l0) >> 16);
    L.u[1] = (__float_as_uint(l3) & MSK) | (__float_as_uint(l2) >> 16);
    L.u[2] = (__float_as_uint(l5) & MSK) | (__float_as_uint(l4) >> 16);
    L.u[3] = (__float_as_uint(l7) & MSK) | (__float_as_uint(l6) >> 16);
    h = H.s; l = L.s;
}

// ---------------- K0: pre-convert W -> bf16 hi/lo images in staged layout ----------------
// img[ch][kq][col][8] bf16: exactly the per-chunk LDS byte order gemm stages.
__global__ __launch_bounds__(256) void conv_w(const float* __restrict__ W,
                                              ushort* __restrict__ hiImg,
                                              ushort* __restrict__ loImg) {
    const int t = blockIdx.x * 256 + threadIdx.x;  // 16384 threads
    const int c  = t & 127;
    const int q  = (t >> 7) & 3;
    const int ch = t >> 9;
    const float* src = W + (size_t)c * E_DIM + ch * 32 + q * 8;
    const f32x4 v0 = *(const f32x4*)src;
    const f32x4 v1 = *(const f32x4*)(src + 4);
    short8v h, l;
    cvt_hilo(v0, v1, h, l);
    const size_t off = ((size_t)(ch * 4 + q) * NP + c) * 8;
    *(short8v*)&hiImg[off] = h;
    *(short8v*)&loImg[off] = l;
}

// ---------------- K1: single-pass bf16-MFMA GEMM, bias fused ----------------
// qk[m][p] = sum_k A[m][k]*W[p][k] + bias[p];  A = context as (S*B,E), m = s*B+b.
// 256 thr = 4 waves; wave w -> cols w*32..+31, all 32 rows. 16x16x32 bf16 MFMA,
// hi/lo split on A (in-kernel cvt) and W (pre-converted images, direct b128 frags).
// A staged via global_load_lds into linear [row][32] f32 with source-granule XOR
// (key=row&7); W staged via fully-linear 1KB gload16 from the images.
__global__ __launch_bounds__(256, 2) void gemm_qk(const float* __restrict__ A,
                                                  const ushort* __restrict__ hiImg,
                                                  const ushort* __restrict__ loImg,
                                                  const float* __restrict__ bias,
                                                  float* __restrict__ qk) {
    __shared__ __align__(16) float  As[2][BMR][BK];   // 8 KB
    __shared__ __align__(16) ushort Whi[2][4][NP][8]; // 16 KB
    __shared__ __align__(16) ushort Wlo[2][4][NP][8]; // 16 KB  (40 KB total)
    const int tid = threadIdx.x;
    const int m0  = blockIdx.x * BMR;
    const int w   = __builtin_amdgcn_readfirstlane(tid >> 6);  // wave id (uniform)
    const int ln  = tid & 63;
    const int lr  = ln >> 3;        // staging row in 8-row group
    const int g8  = ln & 7;         // staging slot granule
    const int row16 = ln & 15;      // frag row/col
    const int kq    = ln >> 4;      // k-quadrant
    const int r7    = row16 & 7;
    const int sg0 = ((((kq << 1) | 0) ^ r7) & 7) << 2;  // A slot offsets (floats)
    const int sg1 = ((((kq << 1) | 1) ^ r7) & 7) << 2;

    // A staging source: wave w covers rows w*8..+7; slot s holds global granule s^(row&7)
    const float*  aS = A + (size_t)(m0 + w * 8 + lr) * E_DIM + ((g8 ^ lr) << 2);
    // W staging source: linear; per-lane = base + ln*16B
    const ushort* hS = hiImg + (size_t)(w * 2) * 512 + ln * 8;
    const ushort* lS = loImg + (size_t)(w * 2) * 512 + ln * 8;

    float bias2[2];
    bias2[0] = bias[w * 32 + row16];
    bias2[1] = bias[w * 32 + 16 + row16];

    f32x4 acc[2][2];
#pragma unroll
    for (int i = 0; i < 2; ++i)
#pragma unroll
        for (int j = 0; j < 2; ++j) acc[i][j] = (f32x4){0.f, 0.f, 0.f, 0.f};

#define STAGE(BUF, CH)                                                          \
    {                                                                           \
        gload16(aS + (size_t)(CH) * BK, &As[BUF][w * 8][0]);                    \
        gload16(hS + (size_t)(CH) * 4096,       (ushort*)Whi[BUF] + (w * 2) * 512);       \
        gload16(hS + (size_t)(CH) * 4096 + 512, (ushort*)Whi[BUF] + (w * 2 + 1) * 512);   \
        gload16(lS + (size_t)(CH) * 4096,       (ushort*)Wlo[BUF] + (w * 2) * 512);       \
        gload16(lS + (size_t)(CH) * 4096 + 512, (ushort*)Wlo[BUF] + (w * 2 + 1) * 512);   \
    }

    STAGE(0, 0)

    for (int ch = 0; ch < NCH; ++ch) {
        const int buf = ch & 1;
        __syncthreads();   // drains vmcnt -> staged chunk valid
        if (ch + 1 < NCH) {
            STAGE(buf ^ 1, ch + 1)
        }
        short8v ah[2], al[2];
#pragma unroll
        for (int fi = 0; fi < 2; ++fi) {
            const float* base = &As[buf][fi * 16 + row16][0];
            const f32x4 v0 = *(const f32x4*)(base + sg0);
            const f32x4 v1 = *(const f32x4*)(base + sg1);
            cvt_hilo(v0, v1, ah[fi], al[fi]);
        }
        short8v wh[2], wl[2];
#pragma unroll
        for (int fj = 0; fj < 2; ++fj) {
            wh[fj] = *(const short8v*)&Whi[buf][kq][w * 32 + fj * 16 + row16][0];
            wl[fj] = *(const short8v*)&Wlo[buf][kq][w * 32 + fj * 16 + row16][0];
        }
#pragma unroll
        for (int fi = 0; fi < 2; ++fi)
#pragma unroll
            for (int fj = 0; fj < 2; ++fj) {
                acc[fi][fj] = __builtin_amdgcn_mfma_f32_16x16x32_bf16(
                    ah[fi], wh[fj], acc[fi][fj], 0, 0, 0);
                acc[fi][fj] = __builtin_amdgcn_mfma_f32_16x16x32_bf16(
                    ah[fi], wl[fj], acc[fi][fj], 0, 0, 0);
                acc[fi][fj] = __builtin_amdgcn_mfma_f32_16x16x32_bf16(
                    al[fi], wh[fj], acc[fi][fj], 0, 0, 0);
            }
    }
#undef STAGE

    // C/D layout (m89): col = lane&15, row = (lane>>4)*4 + r
#pragma unroll
    for (int fi = 0; fi < 2; ++fi)
#pragma unroll
        for (int fj = 0; fj < 2; ++fj) {
#pragma unroll
            for (int r = 0; r < 4; ++r) {
                const int m = m0 + fi * 16 + kq * 4 + r;
                const int p = w * 32 + fj * 16 + row16;
                qk[(size_t)m * NP + p] = acc[fi][fj][r] + bias2[fj];
            }
        }
}

// ---------------- K2: neighbor scores + 2-way softmax (bias already in qk) ----------------
__global__ __launch_bounds__(256) void neighbor_probs(const float* __restrict__ qk,
                                                      float* __restrict__ p0,
                                                      float* __restrict__ p1) {
    const int m = blockIdx.x * 4 + (threadIdx.x >> 6);  // position index m = s*B+b
    const int lane = threadIdx.x & 63;
    const int s = m >> 3;   // / B_DIM
    const int b = m & 7;    // % B_DIM

    const float q = qk[(size_t)m * NP + lane];
    const float kn = (s < S_DIM - 1) ? qk[(size_t)(m + B_DIM) * NP + PD + lane] : 0.f;
    const float kp = (s > 0) ? qk[(size_t)(m - B_DIM) * NP + PD + lane] : 0.f;
    float f = q * kn;   // fwd partial: query[s] . key[s+1]
    float g = q * kp;   // bwd partial: query[s] . key[s-1]
#pragma unroll
    for (int off = 32; off; off >>= 1) {
        f += __shfl_xor(f, off);
        g += __shfl_xor(g, off);
    }
    if (lane == 0) {
        const float s0 = f * (1.f / (float)E_DIM);
        const float s1 = g * (1.f / (float)E_DIM);
        float P0, P1;
        if (s == S_DIM - 1) { P0 = 0.f; P1 = 1.f; }
        else if (s == 0)    { P0 = 1.f; P1 = 0.f; }
        else {
            const float mx = fmaxf(s0, s1);
            const float e0 = __expf(s0 - mx), e1 = __expf(s1 - mx);
            const float inv = 1.f / (e0 + e1);
            P0 = e0 * inv; P1 = e1 * inv;
        }
        p0[b * S_DIM + s] = P0;
        p1[b * S_DIM + s] = P1;
    }
}

// ---------------- K3: combine (flat roll), neighbor_attn out, log, exclusive scan ----------------
__global__ __launch_bounds__(256) void combine_scan(const float* __restrict__ p0,
                                                    const float* __restrict__ p1,
                                                    const float* __restrict__ prior,
                                                    float* __restrict__ out_na,
                                                    float* __restrict__ cs) {
    const int b = blockIdx.x;
    const int tid = threadIdx.x;
    __shared__ float sh[256];

    const int base = b * S_DIM + tid * 8;
    float incl[8];
    float run = 0.f;
#pragma unroll
    for (int u = 0; u < 8; ++u) {
        const int fidx = base + u;
        int nf = fidx + 1;
        if (nf == B_DIM * S_DIM) nf = 0;   // torch .roll on flattened tensor wraps globally
        const float P0 = p0[fidx];
        const float sp = p1[nf];
        const float pr = prior[fidx];
        const float na = pr + (1.f - pr) * sqrtf(P0 * sp + 1e-6f);
        out_na[fidx] = na;
        run += __logf(na);
        incl[u] = run;
    }
    sh[tid] = run;
    __syncthreads();
    for (int off = 1; off < 256; off <<= 1) {
        float v = sh[tid];
        if (tid >= off) v += sh[tid - off];
        __syncthreads();
        sh[tid] = v;
        __syncthreads();
    }
    const float offset = (tid > 0) ? sh[tid - 1] : 0.f;
#pragma unroll
    for (int u = 0; u < 8; ++u) {
        cs[base + u] = offset + ((u > 0) ? incl[u - 1] : 0.f);  // exclusive prefix
    }
}

// ---------------- K4: big output C[b,i,j] = exp(sign*(cs[j]-cs[i])), 0 on diag ----------------
__global__ __launch_bounds__(256) void big_out(const float* __restrict__ cs,
                                               float* __restrict__ out) {
    const int bi = blockIdx.x;          // b*S + i
    const int b = bi >> 11;             // / S_DIM
    const int i = bi & (S_DIM - 1);
    const float ci = cs[b * S_DIM + i];
    const float* crow = cs + (size_t)b * S_DIM;
    float* orow = out + (size_t)bi * S_DIM;
    const int j0 = threadIdx.x * 8;
#pragma unroll
    for (int h = 0; h < 2; ++h) {
        const int j = j0 + h * 4;
        const f32x4 cj = *(const f32x4*)&crow[j];
        f32x4 o;
        {
            const int jj = j + 0; const float m = (jj > i) ? (cj.x - ci) : (ci - cj.x);
            o.x = (jj == i) ? 0.f : __expf(m);
        }
        {
            const int jj = j + 1; const float m = (jj > i) ? (cj.y - ci) : (ci - cj.y);
            o.y = (jj == i) ? 0.f : __expf(m);
        }
        {
            const int jj = j + 2; const float m = (jj > i) ? (cj.z - ci) : (ci - cj.z);
            o.z = (jj == i) ? 0.f : __expf(m);
        }
        {
            const int jj = j + 3; const float m = (jj > i) ? (cj.w - ci) : (ci - cj.w);
            o.w = (jj == i) ? 0.f : __expf(m);
        }
        *(f32x4*)&orow[j] = o;   // regular store (NT store was the r10 regression)
    }
}

extern "C" void kernel_launch(void* const* d_in, const int* in_sizes, int n_in,
                              void* d_out, int out_size, void* d_ws, size_t ws_size,
                              hipStream_t stream) {
    const float* context = (const float*)d_in[0];   // (S,B,E) fp32
    const float* prior   = (const float*)d_in[1];   // (B,S) fp32
    const float* W       = (const float*)d_in[2];   // (128,1024) fp32
    const float* bias    = (const float*)d_in[3];   // (128,) fp32
    float* out = (float*)d_out;

    float* qk = (float*)d_ws;                          // 16384*128 floats (8 MB)
    float* p0 = qk + (size_t)M_TOT * NP;               // 16384 floats
    float* p1 = p0 + M_TOT;                            // 16384 floats
    float* cs = p1 + M_TOT;                            // 16384 floats
    // W bf16 hi/lo images (256 KB each) live in d_out's C-region; conv_w writes,
    // gemm reads, big_out overwrites afterwards (stream-ordered, safe)
    ushort* hiImg = (ushort*)out;                      // 128K ushorts
    ushort* loImg = hiImg + (size_t)NP * E_DIM;        // 128K ushorts
    float* na_out = out + (size_t)B_DIM * S_DIM * S_DIM;  // second output

    conv_w<<<64, 256, 0, stream>>>(W, hiImg, loImg);
    gemm_qk<<<M_TOT / BMR, 256, 0, stream>>>(context, hiImg, loImg, bias, qk);
    neighbor_probs<<<M_TOT / 4, 256, 0, stream>>>(qk, p0, p1);
    combine_scan<<<B_DIM, 256, 0, stream>>>(p0, p1, prior, na_out, cs);
    big_out<<<M_TOT, 256, 0, stream>>>(cs, out);
}

// Round 12
// 63.950 us; speedup vs baseline: 1.3238x; 1.0085x over previous
//
#include <hip/hip_runtime.h>
#include <cstdint>
#include <cstddef>

#define E_DIM 1024
#define PD 64            // proj dim
#define NP 128           // 2*proj dim
#define B_DIM 8
#define S_DIM 2048
#define M_TOT (B_DIM * S_DIM)   // 16384

#define BMR 32           // rows per block
#define BK 32
#define NCH (E_DIM / BK) // 32 chunks

typedef __attribute__((ext_vector_type(8))) short short8v;  // 8 bf16 (4 VGPR)
typedef __attribute__((ext_vector_type(4))) float f32x4;    // MFMA acc / vec IO

__device__ __forceinline__ void gload16(const void* g, void* l) {
    __builtin_amdgcn_global_load_lds(
        (const __attribute__((address_space(1))) unsigned int*)g,
        (__attribute__((address_space(3))) unsigned int*)(uintptr_t)l,
        16, 0, 0);
}

// two-fold truncation split: a = hi + lo at the fp32->bf16 boundary
__device__ __forceinline__ void cvt_hilo(const f32x4 v0, const f32x4 v1,
                                         short8v& h, short8v& l) {
    const unsigned MSK = 0xFFFF0000u;
    unsigned a0 = __float_as_uint(v0.x), a1 = __float_as_uint(v0.y);
    unsigned a2 = __float_as_uint(v0.z), a3 = __float_as_uint(v0.w);
    unsigned a4 = __float_as_uint(v1.x), a5 = __float_as_uint(v1.y);
    unsigned a6 = __float_as_uint(v1.z), a7 = __float_as_uint(v1.w);
    float l0 = v0.x - __uint_as_float(a0 & MSK);
    float l1 = v0.y - __uint_as_float(a1 & MSK);
    float l2 = v0.z - __uint_as_float(a2 & MSK);
    float l3 = v0.w - __uint_as_float(a3 & MSK);
    float l4 = v1.x - __uint_as_float(a4 & MSK);
    float l5 = v1.y - __uint_as_float(a5 & MSK);
    float l6 = v1.z - __uint_as_float(a6 & MSK);
    float l7 = v1.w - __uint_as_float(a7 & MSK);
    union { unsigned u[4]; short8v s; } H, L;
    H.u[0] = (a1 & MSK) | (a0 >> 16);
    H.u[1] = (a3 & MSK) | (a2 >> 16);
    H.u[2] = (a5 & MSK) | (a4 >> 16);
    H.u[3] = (a7 & MSK) | (a6 >> 16);
    L.u[0] = (__float_as_uint(l1) & MSK) | (__float_as_uint(l0) >> 16);
    L.u[1] = (__float_as_uint(l3) & MSK) | (__float_as_uint(l2) >> 16);
    L.u[2] = (__float_as_uint(l5) & MSK) | (__float_as_uint(l4) >> 16);
    L.u[3] = (__float_as_uint(l7) & MSK) | (__float_as_uint(l6) >> 16);
    h = H.s; l = L.s;
}

// ---------------- K0: pre-convert W -> bf16 hi/lo images in staged layout ----------------
// img[ch][kq][col][8] bf16: exactly the per-chunk LDS byte order gemm stages.
__global__ __launch_bounds__(256) void conv_w(const float* __restrict__ W,
                                              ushort* __restrict__ hiImg,
                                              ushort* __restrict__ loImg) {
    const int t = blockIdx.x * 256 + threadIdx.x;  // 16384 threads
    const int c  = t & 127;
    const int q  = (t >> 7) & 3;
    const int ch = t >> 9;
    const float* src = W + (size_t)c * E_DIM + ch * 32 + q * 8;
    const f32x4 v0 = *(const f32x4*)src;
    const f32x4 v1 = *(const f32x4*)(src + 4);
    short8v h, l;
    cvt_hilo(v0, v1, h, l);
    const size_t off = ((size_t)(ch * 4 + q) * NP + c) * 8;
    *(short8v*)&hiImg[off] = h;
    *(short8v*)&loImg[off] = l;
}

// ---------------- K1: single-pass bf16-MFMA GEMM, bias fused ----------------
// 3-deep LDS pipeline with counted vmcnt (T4): STAGE(ch+2) issued right after the
// barrier; the wait leaves the next chunk's 5 loads in flight (vmcnt(5)), draining
// to 0 only on the last chunk. In-order VMEM retirement => vmcnt(5) proves the
// current chunk's loads landed. Raw s_barrier (no compiler vmcnt(0) drain).
__global__ __launch_bounds__(256, 2) void gemm_qk(const float* __restrict__ A,
                                                  const ushort* __restrict__ hiImg,
                                                  const ushort* __restrict__ loImg,
                                                  const float* __restrict__ bias,
                                                  float* __restrict__ qk) {
    __shared__ __align__(16) float  As[3][BMR][BK];   // 12 KB
    __shared__ __align__(16) ushort Whi[3][4][NP][8]; // 24 KB
    __shared__ __align__(16) ushort Wlo[3][4][NP][8]; // 24 KB  (60 KB total)
    const int tid = threadIdx.x;
    const int m0  = blockIdx.x * BMR;
    const int w   = __builtin_amdgcn_readfirstlane(tid >> 6);  // wave id (uniform)
    const int ln  = tid & 63;
    const int lr  = ln >> 3;        // staging row in 8-row group
    const int g8  = ln & 7;         // staging slot granule
    const int row16 = ln & 15;      // frag row/col
    const int kq    = ln >> 4;      // k-quadrant
    const int r7    = row16 & 7;
    const int sg0 = ((((kq << 1) | 0) ^ r7) & 7) << 2;  // A slot offsets (floats)
    const int sg1 = ((((kq << 1) | 1) ^ r7) & 7) << 2;

    // A staging source: wave w covers rows w*8..+7; slot s holds global granule s^(row&7)
    const float*  aS = A + (size_t)(m0 + w * 8 + lr) * E_DIM + ((g8 ^ lr) << 2);
    // W staging source: linear; per-lane = base + ln*16B
    const ushort* hS = hiImg + (size_t)(w * 2) * 512 + ln * 8;
    const ushort* lS = loImg + (size_t)(w * 2) * 512 + ln * 8;

    float bias2[2];
    bias2[0] = bias[w * 32 + row16];
    bias2[1] = bias[w * 32 + 16 + row16];

    f32x4 acc[2][2];
#pragma unroll
    for (int i = 0; i < 2; ++i)
#pragma unroll
        for (int j = 0; j < 2; ++j) acc[i][j] = (f32x4){0.f, 0.f, 0.f, 0.f};

#define STAGE(BUF, CH)                                                          \
    {                                                                           \
        gload16(aS + (size_t)(CH) * BK, &As[BUF][w * 8][0]);                    \
        gload16(hS + (size_t)(CH) * 4096,       (ushort*)Whi[BUF] + (w * 2) * 512);       \
        gload16(hS + (size_t)(CH) * 4096 + 512, (ushort*)Whi[BUF] + (w * 2 + 1) * 512);   \
        gload16(lS + (size_t)(CH) * 4096,       (ushort*)Wlo[BUF] + (w * 2) * 512);       \
        gload16(lS + (size_t)(CH) * 4096 + 512, (ushort*)Wlo[BUF] + (w * 2 + 1) * 512);   \
    }

    STAGE(0, 0)
    STAGE(1, 1)

#pragma unroll
    for (int ch = 0; ch < NCH; ++ch) {
        const int buf = ch % 3;
        // wait for THIS chunk's loads: everything younger than the next chunk's 5
        if (ch == NCH - 1) {
            asm volatile("s_waitcnt vmcnt(0)" ::: "memory");
        } else {
            asm volatile("s_waitcnt vmcnt(5)" ::: "memory");
        }
        __builtin_amdgcn_sched_barrier(0);
        __builtin_amdgcn_s_barrier();
        if (ch + 2 < NCH) {
            STAGE((ch + 2) % 3, ch + 2)
        }
        short8v ah[2], al[2];
#pragma unroll
        for (int fi = 0; fi < 2; ++fi) {
            const float* base = &As[buf][fi * 16 + row16][0];
            const f32x4 v0 = *(const f32x4*)(base + sg0);
            const f32x4 v1 = *(const f32x4*)(base + sg1);
            cvt_hilo(v0, v1, ah[fi], al[fi]);
        }
        short8v wh[2], wl[2];
#pragma unroll
        for (int fj = 0; fj < 2; ++fj) {
            wh[fj] = *(const short8v*)&Whi[buf][kq][w * 32 + fj * 16 + row16][0];
            wl[fj] = *(const short8v*)&Wlo[buf][kq][w * 32 + fj * 16 + row16][0];
        }
#pragma unroll
        for (int fi = 0; fi < 2; ++fi)
#pragma unroll
            for (int fj = 0; fj < 2; ++fj) {
                acc[fi][fj] = __builtin_amdgcn_mfma_f32_16x16x32_bf16(
                    ah[fi], wh[fj], acc[fi][fj], 0, 0, 0);
                acc[fi][fj] = __builtin_amdgcn_mfma_f32_16x16x32_bf16(
                    ah[fi], wl[fj], acc[fi][fj], 0, 0, 0);
                acc[fi][fj] = __builtin_amdgcn_mfma_f32_16x16x32_bf16(
                    al[fi], wh[fj], acc[fi][fj], 0, 0, 0);
            }
    }
#undef STAGE

    // C/D layout (m89): col = lane&15, row = (lane>>4)*4 + r
#pragma unroll
    for (int fi = 0; fi < 2; ++fi)
#pragma unroll
        for (int fj = 0; fj < 2; ++fj) {
#pragma unroll
            for (int r = 0; r < 4; ++r) {
                const int m = m0 + fi * 16 + kq * 4 + r;
                const int p = w * 32 + fj * 16 + row16;
                qk[(size_t)m * NP + p] = acc[fi][fj][r] + bias2[fj];
            }
        }
}

// ---------------- K2: neighbor scores + 2-way softmax (bias already in qk) ----------------
__global__ __launch_bounds__(256) void neighbor_probs(const float* __restrict__ qk,
                                                      float* __restrict__ p0,
                                                      float* __restrict__ p1) {
    const int m = blockIdx.x * 4 + (threadIdx.x >> 6);  // position index m = s*B+b
    const int lane = threadIdx.x & 63;
    const int s = m >> 3;   // / B_DIM
    const int b = m & 7;    // % B_DIM

    const float q = qk[(size_t)m * NP + lane];
    const float kn = (s < S_DIM - 1) ? qk[(size_t)(m + B_DIM) * NP + PD + lane] : 0.f;
    const float kp = (s > 0) ? qk[(size_t)(m - B_DIM) * NP + PD + lane] : 0.f;
    float f = q * kn;   // fwd partial: query[s] . key[s+1]
    float g = q * kp;   // bwd partial: query[s] . key[s-1]
#pragma unroll
    for (int off = 32; off; off >>= 1) {
        f += __shfl_xor(f, off);
        g += __shfl_xor(g, off);
    }
    if (lane == 0) {
        const float s0 = f * (1.f / (float)E_DIM);
        const float s1 = g * (1.f / (float)E_DIM);
        float P0, P1;
        if (s == S_DIM - 1) { P0 = 0.f; P1 = 1.f; }
        else if (s == 0)    { P0 = 1.f; P1 = 0.f; }
        else {
            const float mx = fmaxf(s0, s1);
            const float e0 = __expf(s0 - mx), e1 = __expf(s1 - mx);
            const float inv = 1.f / (e0 + e1);
            P0 = e0 * inv; P1 = e1 * inv;
        }
        p0[b * S_DIM + s] = P0;
        p1[b * S_DIM + s] = P1;
    }
}

// ---------------- K3: combine (flat roll), neighbor_attn out, log, exclusive scan ----------------
__global__ __launch_bounds__(256) void combine_scan(const float* __restrict__ p0,
                                                    const float* __restrict__ p1,
                                                    const float* __restrict__ prior,
                                                    float* __restrict__ out_na,
                                                    float* __restrict__ cs) {
    const int b = blockIdx.x;
    const int tid = threadIdx.x;
    __shared__ float sh[256];

    const int base = b * S_DIM + tid * 8;
    float incl[8];
    float run = 0.f;
#pragma unroll
    for (int u = 0; u < 8; ++u) {
        const int fidx = base + u;
        int nf = fidx + 1;
        if (nf == B_DIM * S_DIM) nf = 0;   // torch .roll on flattened tensor wraps globally
        const float P0 = p0[fidx];
        const float sp = p1[nf];
        const float pr = prior[fidx];
        const float na = pr + (1.f - pr) * sqrtf(P0 * sp + 1e-6f);
        out_na[fidx] = na;
        run += __logf(na);
        incl[u] = run;
    }
    sh[tid] = run;
    __syncthreads();
    for (int off = 1; off < 256; off <<= 1) {
        float v = sh[tid];
        if (tid >= off) v += sh[tid - off];
        __syncthreads();
        sh[tid] = v;
        __syncthreads();
    }
    const float offset = (tid > 0) ? sh[tid - 1] : 0.f;
#pragma unroll
    for (int u = 0; u < 8; ++u) {
        cs[base + u] = offset + ((u > 0) ? incl[u - 1] : 0.f);  // exclusive prefix
    }
}

// ---------------- K4: big output C[b,i,j] = exp(sign*(cs[j]-cs[i])), 0 on diag ----------------
__global__ __launch_bounds__(256) void big_out(const float* __restrict__ cs,
                                               float* __restrict__ out) {
    const int bi = blockIdx.x;          // b*S + i
    const int b = bi >> 11;             // / S_DIM
    const int i = bi & (S_DIM - 1);
    const float ci = cs[b * S_DIM + i];
    const float* crow = cs + (size_t)b * S_DIM;
    float* orow = out + (size_t)bi * S_DIM;
    const int j0 = threadIdx.x * 8;
#pragma unroll
    for (int h = 0; h < 2; ++h) {
        const int j = j0 + h * 4;
        const f32x4 cj = *(const f32x4*)&crow[j];
        f32x4 o;
        {
            const int jj = j + 0; const float m = (jj > i) ? (cj.x - ci) : (ci - cj.x);
            o.x = (jj == i) ? 0.f : __expf(m);
        }
        {
            const int jj = j + 1; const float m = (jj > i) ? (cj.y - ci) : (ci - cj.y);
            o.y = (jj == i) ? 0.f : __expf(m);
        }
        {
            const int jj = j + 2; const float m = (jj > i) ? (cj.z - ci) : (ci - cj.z);
            o.z = (jj == i) ? 0.f : __expf(m);
        }
        {
            const int jj = j + 3; const float m = (jj > i) ? (cj.w - ci) : (ci - cj.w);
            o.w = (jj == i) ? 0.f : __expf(m);
        }
        *(f32x4*)&orow[j] = o;   // regular store (NT store was the r10 regression)
    }
}

extern "C" void kernel_launch(void* const* d_in, const int* in_sizes, int n_in,
                              void* d_out, int out_size, void* d_ws, size_t ws_size,
                              hipStream_t stream) {
    const float* context = (const float*)d_in[0];   // (S,B,E) fp32
    const float* prior   = (const float*)d_in[1];   // (B,S) fp32
    const float* W       = (const float*)d_in[2];   // (128,1024) fp32
    const float* bias    = (const float*)d_in[3];   // (128,) fp32
    float* out = (float*)d_out;

    float* qk = (float*)d_ws;                          // 16384*128 floats (8 MB)
    float* p0 = qk + (size_t)M_TOT * NP;               // 16384 floats
    float* p1 = p0 + M_TOT;                            // 16384 floats
    float* cs = p1 + M_TOT;                            // 16384 floats
    // W bf16 hi/lo images (256 KB each) live in d_out's C-region; conv_w writes,
    // gemm reads, big_out overwrites afterwards (stream-ordered, safe)
    ushort* hiImg = (ushort*)out;                      // 128K ushorts
    ushort* loImg = hiImg + (size_t)NP * E_DIM;        // 128K ushorts
    float* na_out = out + (size_t)B_DIM * S_DIM * S_DIM;  // second output

    conv_w<<<64, 256, 0, stream>>>(W, hiImg, loImg);
    gemm_qk<<<M_TOT / BMR, 256, 0, stream>>>(context, hiImg, loImg, bias, qk);
    neighbor_probs<<<M_TOT / 4, 256, 0, stream>>>(qk, p0, p1);
    combine_scan<<<B_DIM, 256, 0, stream>>>(p0, p1, prior, na_out, cs);
    big_out<<<M_TOT, 256, 0, stream>>>(cs, out);
}